// Round 3
// baseline (164.309 us; speedup 1.0000x reference)
//
#include <hip/hip_runtime.h>
#include <hip/hip_bf16.h>

// Segment-mean over sorted index.
// inp: [N_ROWS, D] fp32, index: [N_ROWS] int32 (sorted), out: [N_SEG, D] fp32.
//
// Pass 1: boundary-scatter -> seg_start[n_seg+1] (first row with index >= s).
//         prev index via __shfl_up (one global load per row).
// Pass 2: one wave per segment. Lane l covers column quad (l&31), row parity
//         (l>>5). float4 loads (16 B/lane, 1 KB contiguous per instruction),
//         unrolled x4 -> 4 independent accumulator chains, 4 loads in flight,
//         per-iter offsets +1/2/3 KB fit the 13-bit signed immediate.
//         shfl_xor(32) combine; lanes 0..31 write the float4 mean.

#define WAVES_PER_BLOCK 4

__global__ __launch_bounds__(256)
void seg_bounds_kernel(const int* __restrict__ index, int* __restrict__ seg_start,
                       int n_rows, int n_seg) {
    const int r = blockIdx.x * blockDim.x + threadIdx.x;
    if (r >= n_rows) return;
    const int lane = threadIdx.x & 63;
    const int cur  = index[r];
    int prev = __shfl_up(cur, 1, 64);
    if (lane == 0) prev = (r == 0) ? -1 : index[r - 1];
    for (int s = prev + 1; s <= cur; ++s) seg_start[s] = r;
    if (r == n_rows - 1) {
        for (int s = cur + 1; s <= n_seg; ++s) seg_start[s] = n_rows;
    }
}

__global__ __launch_bounds__(256)
void ScatterReduceAggregation_86311662780467_kernel(
    const float* __restrict__ inp,
    const int*   __restrict__ seg_start,
    float*       __restrict__ out,
    int n_seg) {

    const int wave_in_block = threadIdx.x >> 6;
    const int lane          = threadIdx.x & 63;
    const int seg = blockIdx.x * WAVES_PER_BLOCK + wave_in_block;
    if (seg >= n_seg) return;

    const int start = seg_start[seg];
    const int end   = seg_start[seg + 1];

    const int half  = lane >> 5;   // row parity this lane covers
    const int quad  = lane & 31;   // which float4 of the row (D=128 -> 32 quads)

    const float4* __restrict__ inp4 = reinterpret_cast<const float4*>(inp) + quad;

    float4 a0 = make_float4(0.f, 0.f, 0.f, 0.f);
    float4 a1 = make_float4(0.f, 0.f, 0.f, 0.f);
    float4 a2 = make_float4(0.f, 0.f, 0.f, 0.f);
    float4 a3 = make_float4(0.f, 0.f, 0.f, 0.f);

    int r = start + half;
    // main: 4 loads in flight (rows r, r+2, r+4, r+6 for this parity)
    for (; r + 6 < end; r += 8) {
        float4 v0 = inp4[(size_t)r * 32];
        float4 v1 = inp4[(size_t)(r + 2) * 32];
        float4 v2 = inp4[(size_t)(r + 4) * 32];
        float4 v3 = inp4[(size_t)(r + 6) * 32];
        a0.x += v0.x; a0.y += v0.y; a0.z += v0.z; a0.w += v0.w;
        a1.x += v1.x; a1.y += v1.y; a1.z += v1.z; a1.w += v1.w;
        a2.x += v2.x; a2.y += v2.y; a2.z += v2.z; a2.w += v2.w;
        a3.x += v3.x; a3.y += v3.y; a3.z += v3.z; a3.w += v3.w;
    }
    // epilogue: at most one x2 step + one x1 step
    for (; r + 2 < end; r += 4) {
        float4 v0 = inp4[(size_t)r * 32];
        float4 v1 = inp4[(size_t)(r + 2) * 32];
        a0.x += v0.x; a0.y += v0.y; a0.z += v0.z; a0.w += v0.w;
        a1.x += v1.x; a1.y += v1.y; a1.z += v1.z; a1.w += v1.w;
    }
    if (r < end) {
        float4 v0 = inp4[(size_t)r * 32];
        a2.x += v0.x; a2.y += v0.y; a2.z += v0.z; a2.w += v0.w;
    }

    a0.x += a1.x; a0.y += a1.y; a0.z += a1.z; a0.w += a1.w;
    a2.x += a3.x; a2.y += a3.y; a2.z += a3.z; a2.w += a3.w;
    a0.x += a2.x; a0.y += a2.y; a0.z += a2.z; a0.w += a2.w;

    // combine the two row-parity halves (lane l <-> lane l^32)
    a0.x += __shfl_xor(a0.x, 32, 64);
    a0.y += __shfl_xor(a0.y, 32, 64);
    a0.z += __shfl_xor(a0.z, 32, 64);
    a0.w += __shfl_xor(a0.w, 32, 64);

    const int cnt = end - start;
    const float inv = (cnt > 0) ? (1.0f / (float)cnt) : 0.0f;

    if (half == 0) {
        float4 o;
        o.x = a0.x * inv; o.y = a0.y * inv; o.z = a0.z * inv; o.w = a0.w * inv;
        reinterpret_cast<float4*>(out)[(size_t)seg * 32 + quad] = o;
    }
}

// Fallback (no workspace): in-kernel binary search, float4 path.
__global__ __launch_bounds__(256)
void seg_mean_search_kernel(
    const float* __restrict__ inp,
    const int*   __restrict__ index,
    float*       __restrict__ out,
    int n_rows, int n_seg) {

    const int wave_in_block = threadIdx.x >> 6;
    const int lane          = threadIdx.x & 63;
    const int seg = blockIdx.x * WAVES_PER_BLOCK + wave_in_block;
    if (seg >= n_seg) return;

    int lo = 0, hi = n_rows;
    while (lo < hi) { int mid = (lo + hi) >> 1; if (index[mid] < seg) lo = mid + 1; else hi = mid; }
    const int start = lo;
    hi = n_rows;
    while (lo < hi) { int mid = (lo + hi) >> 1; if (index[mid] < seg + 1) lo = mid + 1; else hi = mid; }
    const int end = lo;

    const int half = lane >> 5;
    const int quad = lane & 31;
    const float4* __restrict__ inp4 = reinterpret_cast<const float4*>(inp) + quad;

    float4 a0 = make_float4(0.f, 0.f, 0.f, 0.f);
    float4 a1 = make_float4(0.f, 0.f, 0.f, 0.f);
    int r = start + half;
    for (; r + 2 < end; r += 4) {
        float4 v0 = inp4[(size_t)r * 32];
        float4 v1 = inp4[(size_t)(r + 2) * 32];
        a0.x += v0.x; a0.y += v0.y; a0.z += v0.z; a0.w += v0.w;
        a1.x += v1.x; a1.y += v1.y; a1.z += v1.z; a1.w += v1.w;
    }
    if (r < end) {
        float4 v0 = inp4[(size_t)r * 32];
        a0.x += v0.x; a0.y += v0.y; a0.z += v0.z; a0.w += v0.w;
    }
    a0.x += a1.x; a0.y += a1.y; a0.z += a1.z; a0.w += a1.w;
    a0.x += __shfl_xor(a0.x, 32, 64);
    a0.y += __shfl_xor(a0.y, 32, 64);
    a0.z += __shfl_xor(a0.z, 32, 64);
    a0.w += __shfl_xor(a0.w, 32, 64);

    const int cnt = end - start;
    const float inv = (cnt > 0) ? (1.0f / (float)cnt) : 0.0f;
    if (half == 0) {
        float4 o;
        o.x = a0.x * inv; o.y = a0.y * inv; o.z = a0.z * inv; o.w = a0.w * inv;
        reinterpret_cast<float4*>(out)[(size_t)seg * 32 + quad] = o;
    }
}

extern "C" void kernel_launch(void* const* d_in, const int* in_sizes, int n_in,
                              void* d_out, int out_size, void* d_ws, size_t ws_size,
                              hipStream_t stream) {
    const float* inp   = (const float*)d_in[0];
    const int*   index = (const int*)d_in[1];
    float* out = (float*)d_out;

    const int n_rows = in_sizes[1];
    const int d      = in_sizes[0] / n_rows;   // = 128
    const int n_seg  = out_size / d;           // = 50000

    const int blocks = (n_seg + WAVES_PER_BLOCK - 1) / WAVES_PER_BLOCK;
    const size_t need = (size_t)(n_seg + 1) * sizeof(int);

    if (ws_size >= need) {
        int* seg_start = (int*)d_ws;
        const int bblocks = (n_rows + 255) / 256;
        seg_bounds_kernel<<<bblocks, 256, 0, stream>>>(index, seg_start, n_rows, n_seg);
        ScatterReduceAggregation_86311662780467_kernel<<<blocks, 64 * WAVES_PER_BLOCK, 0, stream>>>(
            inp, seg_start, out, n_seg);
    } else {
        seg_mean_search_kernel<<<blocks, 64 * WAVES_PER_BLOCK, 0, stream>>>(
            inp, index, out, n_rows, n_seg);
    }
}

// Round 5
// 148.630 us; speedup vs baseline: 1.1055x; 1.1055x over previous
//
#include <hip/hip_runtime.h>
#include <hip/hip_bf16.h>

// Segment-mean over sorted index.
// inp: [N_ROWS, D] fp32, index: [N_ROWS] int32 (sorted), out: [N_SEG, D] fp32.
//
// Pass 1: boundary-scatter -> seg_start[n_seg+1] (first row with index >= s).
// Pass 2: one wave per segment. Lane l covers column quad (l&31), row parity
//         (l>>5). Nontemporal float4 loads (16 B/lane, 1 KB/instruction,
//         streaming hint: input is read exactly once, 3.2x L3 size),
//         unrolled x4. shfl_xor(32) combine; lanes 0..31 write float4 (nt).
//
// NOTE: __builtin_nontemporal_load needs a NATIVE vector type, not
// HIP_vector_type — use ext_vector_type(4) float.

typedef float f32x4 __attribute__((ext_vector_type(4)));

#define WAVES_PER_BLOCK 4

__global__ __launch_bounds__(256)
void seg_bounds_kernel(const int* __restrict__ index, int* __restrict__ seg_start,
                       int n_rows, int n_seg) {
    const int r = blockIdx.x * blockDim.x + threadIdx.x;
    if (r >= n_rows) return;
    const int lane = threadIdx.x & 63;
    const int cur  = index[r];
    int prev = __shfl_up(cur, 1, 64);
    if (lane == 0) prev = (r == 0) ? -1 : index[r - 1];
    for (int s = prev + 1; s <= cur; ++s) seg_start[s] = r;
    if (r == n_rows - 1) {
        for (int s = cur + 1; s <= n_seg; ++s) seg_start[s] = n_rows;
    }
}

__global__ __launch_bounds__(256)
void ScatterReduceAggregation_86311662780467_kernel(
    const float* __restrict__ inp,
    const int*   __restrict__ seg_start,
    float*       __restrict__ out,
    int n_seg) {

    const int wave_in_block = threadIdx.x >> 6;
    const int lane          = threadIdx.x & 63;
    int seg = blockIdx.x * WAVES_PER_BLOCK + wave_in_block;
    if (seg >= n_seg) return;
    seg = __builtin_amdgcn_readfirstlane(seg);   // wave-uniform -> SGPR -> s_load bounds

    const int start = seg_start[seg];
    const int end   = seg_start[seg + 1];

    const int half  = lane >> 5;   // row parity this lane covers
    const int quad  = lane & 31;   // which float4 of the row (D=128 -> 32 quads)

    const f32x4* __restrict__ inp4 = reinterpret_cast<const f32x4*>(inp) + quad;

    f32x4 a0 = (f32x4)0.0f;
    f32x4 a1 = (f32x4)0.0f;
    f32x4 a2 = (f32x4)0.0f;
    f32x4 a3 = (f32x4)0.0f;

    int r = start + half;
    for (; r + 6 < end; r += 8) {
        f32x4 v0 = __builtin_nontemporal_load(&inp4[(size_t)r * 32]);
        f32x4 v1 = __builtin_nontemporal_load(&inp4[(size_t)(r + 2) * 32]);
        f32x4 v2 = __builtin_nontemporal_load(&inp4[(size_t)(r + 4) * 32]);
        f32x4 v3 = __builtin_nontemporal_load(&inp4[(size_t)(r + 6) * 32]);
        a0 += v0;
        a1 += v1;
        a2 += v2;
        a3 += v3;
    }
    for (; r + 2 < end; r += 4) {
        f32x4 v0 = __builtin_nontemporal_load(&inp4[(size_t)r * 32]);
        f32x4 v1 = __builtin_nontemporal_load(&inp4[(size_t)(r + 2) * 32]);
        a0 += v0;
        a1 += v1;
    }
    if (r < end) {
        f32x4 v0 = __builtin_nontemporal_load(&inp4[(size_t)r * 32]);
        a2 += v0;
    }

    a0 += a1;
    a2 += a3;
    a0 += a2;

    // combine the two row-parity halves (lane l <-> lane l^32)
    a0.x += __shfl_xor(a0.x, 32, 64);
    a0.y += __shfl_xor(a0.y, 32, 64);
    a0.z += __shfl_xor(a0.z, 32, 64);
    a0.w += __shfl_xor(a0.w, 32, 64);

    const int cnt = end - start;
    const float inv = (cnt > 0) ? (1.0f / (float)cnt) : 0.0f;

    if (half == 0) {
        f32x4 o = a0 * inv;
        __builtin_nontemporal_store(o, &reinterpret_cast<f32x4*>(out)[(size_t)seg * 32 + quad]);
    }
}

// Fallback (no workspace): in-kernel binary search, float4 path.
__global__ __launch_bounds__(256)
void seg_mean_search_kernel(
    const float* __restrict__ inp,
    const int*   __restrict__ index,
    float*       __restrict__ out,
    int n_rows, int n_seg) {

    const int wave_in_block = threadIdx.x >> 6;
    const int lane          = threadIdx.x & 63;
    const int seg = blockIdx.x * WAVES_PER_BLOCK + wave_in_block;
    if (seg >= n_seg) return;

    int lo = 0, hi = n_rows;
    while (lo < hi) { int mid = (lo + hi) >> 1; if (index[mid] < seg) lo = mid + 1; else hi = mid; }
    const int start = lo;
    hi = n_rows;
    while (lo < hi) { int mid = (lo + hi) >> 1; if (index[mid] < seg + 1) lo = mid + 1; else hi = mid; }
    const int end = lo;

    const int half = lane >> 5;
    const int quad = lane & 31;
    const f32x4* __restrict__ inp4 = reinterpret_cast<const f32x4*>(inp) + quad;

    f32x4 a0 = (f32x4)0.0f;
    f32x4 a1 = (f32x4)0.0f;
    int r = start + half;
    for (; r + 2 < end; r += 4) {
        f32x4 v0 = inp4[(size_t)r * 32];
        f32x4 v1 = inp4[(size_t)(r + 2) * 32];
        a0 += v0;
        a1 += v1;
    }
    if (r < end) {
        f32x4 v0 = inp4[(size_t)r * 32];
        a0 += v0;
    }
    a0 += a1;
    a0.x += __shfl_xor(a0.x, 32, 64);
    a0.y += __shfl_xor(a0.y, 32, 64);
    a0.z += __shfl_xor(a0.z, 32, 64);
    a0.w += __shfl_xor(a0.w, 32, 64);

    const int cnt = end - start;
    const float inv = (cnt > 0) ? (1.0f / (float)cnt) : 0.0f;
    if (half == 0) {
        f32x4 o = a0 * inv;
        reinterpret_cast<f32x4*>(out)[(size_t)seg * 32 + quad] = o;
    }
}

extern "C" void kernel_launch(void* const* d_in, const int* in_sizes, int n_in,
                              void* d_out, int out_size, void* d_ws, size_t ws_size,
                              hipStream_t stream) {
    const float* inp   = (const float*)d_in[0];
    const int*   index = (const int*)d_in[1];
    float* out = (float*)d_out;

    const int n_rows = in_sizes[1];
    const int d      = in_sizes[0] / n_rows;   // = 128
    const int n_seg  = out_size / d;           // = 50000

    const int blocks = (n_seg + WAVES_PER_BLOCK - 1) / WAVES_PER_BLOCK;
    const size_t need = (size_t)(n_seg + 1) * sizeof(int);

    if (ws_size >= need) {
        int* seg_start = (int*)d_ws;
        const int bblocks = (n_rows + 255) / 256;
        seg_bounds_kernel<<<bblocks, 256, 0, stream>>>(index, seg_start, n_rows, n_seg);
        ScatterReduceAggregation_86311662780467_kernel<<<blocks, 64 * WAVES_PER_BLOCK, 0, stream>>>(
            inp, seg_start, out, n_seg);
    } else {
        seg_mean_search_kernel<<<blocks, 64 * WAVES_PER_BLOCK, 0, stream>>>(
            inp, index, out, n_rows, n_seg);
    }
}